// Round 1
// baseline (3127.930 us; speedup 1.0000x reference)
//
#include <hip/hip_runtime.h>

// RandomProjectionQuantizer: out[n] = argmin_j || x_n @ W^T - c_j ||^2
//   == argmin_j ( c2[j] - 2 * t_n . c_j )   (row-constant ||t||^2 dropped)
//
// Shapes: X (8192,320) f32, W (512,320) f32, CB (8192,512) f32, out (8192) i32.
// All fp32 exact-path (no fp32 MFMA on CDNA4; bf16 split deferred until
// tie-gap stats are verified). ws: targets (8192*512 f32) + c2 (8192 f32).

#define D_IN      320
#define CODE_DIM  512
#define NUM_CODES 8192
#define N_ROWS    8192

// ---------------------------------------------------------------- c2 kernel
// one wave (64 lanes) per code row: c2[j] = sum_k CB[j][k]^2
__global__ __launch_bounds__(256) void c2_kernel(const float* __restrict__ cb,
                                                 float* __restrict__ c2) {
    int wave = (blockIdx.x * blockDim.x + threadIdx.x) >> 6;
    int lane = threadIdx.x & 63;
    if (wave >= NUM_CODES) return;
    const float* row = cb + (size_t)wave * CODE_DIM;
    float s = 0.f;
#pragma unroll
    for (int i = 0; i < CODE_DIM / 64; ++i) {
        float v = row[lane + 64 * i];
        s += v * v;
    }
#pragma unroll
    for (int off = 32; off > 0; off >>= 1) s += __shfl_down(s, off, 64);
    if (lane == 0) c2[wave] = s;
}

// ------------------------------------------------------------ projection
// T = X @ W^T : M=8192, N=512, K=320. 64x64 tile, 256 thr, 4x4 microtile.
#define PB_M 64
#define PB_N 64
#define PB_K 32
#define PLD  (PB_K + 4)   // 36: stride%32==4 -> conflict-free scalar cols

__global__ __launch_bounds__(256) void proj_kernel(const float* __restrict__ X,
                                                   const float* __restrict__ W,
                                                   float* __restrict__ T) {
    __shared__ float Xs[PB_M][PLD];
    __shared__ float Wsh[PB_N][PLD];
    const int bm = blockIdx.x;          // 0..127
    const int bn = blockIdx.y;          // 0..7
    const int tid = threadIdx.x;
    const int tx = tid & 15;            // col group (cols tx+16j)
    const int ty = tid >> 4;            // row group (rows ty+16i)
    float acc[4][4] = {};
    for (int kc = 0; kc < D_IN; kc += PB_K) {
#pragma unroll
        for (int it = 0; it < 2; ++it) {
            int idx = tid + 256 * it;        // 0..511 -> 64 rows x 8 float4
            int r   = idx >> 3;
            int kp  = (idx & 7) * 4;
            *(float4*)&Xs[r][kp] =
                *(const float4*)(X + (size_t)(bm * PB_M + r) * D_IN + kc + kp);
            *(float4*)&Wsh[r][kp] =
                *(const float4*)(W + (size_t)(bn * PB_N + r) * D_IN + kc + kp);
        }
        __syncthreads();
#pragma unroll
        for (int kk = 0; kk < PB_K; ++kk) {
            float a[4], b[4];
#pragma unroll
            for (int i = 0; i < 4; ++i) a[i] = Xs[ty + 16 * i][kk];
#pragma unroll
            for (int j = 0; j < 4; ++j) b[j] = Wsh[tx + 16 * j][kk];
#pragma unroll
            for (int i = 0; i < 4; ++i)
#pragma unroll
                for (int j = 0; j < 4; ++j) acc[i][j] += a[i] * b[j];
        }
        __syncthreads();
    }
#pragma unroll
    for (int i = 0; i < 4; ++i)
#pragma unroll
        for (int j = 0; j < 4; ++j)
            T[(size_t)(bm * PB_M + ty + 16 * i) * CODE_DIM + bn * PB_N + tx + 16 * j] =
                acc[i][j];
}

// ----------------------------------------------- fused distance + argmin
// One block owns DB_ROWS rows and sweeps ALL codes -> no cross-block argmin.
// Per code-tile CT: accumulate dot over K in KC chunks (LDS-staged), then
// score = c2 - 2*dot, update per-thread running (best,idx) with first-index
// tie-break; final per-row reduce across the 32 code-groups.
#define DB_ROWS 32
#define CT      256
#define KC      32
#define TLD     (KC + 4)   // 36
#define CLD     (KC + 4)   // 36

__global__ __launch_bounds__(256) void dist_argmin_kernel(
        const float* __restrict__ T, const float* __restrict__ CB,
        const float* __restrict__ c2, int* __restrict__ out) {
    __shared__ float t_lds[DB_ROWS][TLD];   //  4.6 KB
    __shared__ float c_lds[CT][CLD];        // 36.9 KB
    __shared__ float red_v[DB_ROWS][32];    //  4.1 KB
    __shared__ int   red_i[DB_ROWS][32];    //  4.1 KB

    const int tid = threadIdx.x;
    const int rg  = tid & 7;    // rows rg + 8i  (stride-8 -> conflict-free)
    const int cg  = tid >> 3;   // codes cg + 32j (0..31)
    const int rbase = blockIdx.x * DB_ROWS;

    float bestv[4];
    int   besti[4];
#pragma unroll
    for (int i = 0; i < 4; ++i) { bestv[i] = 3.4e38f; besti[i] = 0; }

    for (int ct = 0; ct < NUM_CODES; ct += CT) {
        float acc[4][8] = {};
        for (int kc = 0; kc < CODE_DIM; kc += KC) {
            __syncthreads();   // previous compute done before LDS overwrite
            // stage targets chunk: 32 rows x 32 k = 256 float4, 1/thread
            {
                int r  = tid >> 3;            // 8 float4 per row
                int kp = (tid & 7) * 4;
                *(float4*)&t_lds[r][kp] =
                    *(const float4*)(T + (size_t)(rbase + r) * CODE_DIM + kc + kp);
            }
            // stage code chunk: 256 codes x 32 k = 2048 float4, 8/thread
#pragma unroll
            for (int it = 0; it < 8; ++it) {
                int idx = tid + 256 * it;
                int c   = idx >> 3;
                int kp  = (idx & 7) * 4;
                *(float4*)&c_lds[c][kp] =
                    *(const float4*)(CB + (size_t)(ct + c) * CODE_DIM + kc + kp);
            }
            __syncthreads();
#pragma unroll
            for (int kk = 0; kk < KC; kk += 4) {
                float4 t4[4], c4[8];
#pragma unroll
                for (int i = 0; i < 4; ++i)
                    t4[i] = *(const float4*)&t_lds[rg + 8 * i][kk];
#pragma unroll
                for (int j = 0; j < 8; ++j)
                    c4[j] = *(const float4*)&c_lds[cg + 32 * j][kk];
#pragma unroll
                for (int i = 0; i < 4; ++i)
#pragma unroll
                    for (int j = 0; j < 8; ++j)
                        acc[i][j] += t4[i].x * c4[j].x + t4[i].y * c4[j].y +
                                     t4[i].z * c4[j].z + t4[i].w * c4[j].w;
            }
        }
        // epilogue: scores + running argmin (j ascending => code ascending,
        // strict '<' keeps the earliest index within this thread's stream)
#pragma unroll
        for (int j = 0; j < 8; ++j) {
            int   code = ct + cg + 32 * j;
            float cc   = c2[code];
#pragma unroll
            for (int i = 0; i < 4; ++i) {
                float s = cc - 2.0f * acc[i][j];
                if (s < bestv[i]) { bestv[i] = s; besti[i] = code; }
            }
        }
    }

    __syncthreads();
#pragma unroll
    for (int i = 0; i < 4; ++i) {
        red_v[rg + 8 * i][cg] = bestv[i];
        red_i[rg + 8 * i][cg] = besti[i];
    }
    __syncthreads();
    if (tid < DB_ROWS) {
        float bv = red_v[tid][0];
        int   bi = red_i[tid][0];
#pragma unroll
        for (int c = 1; c < 32; ++c) {
            float v = red_v[tid][c];
            int   idx = red_i[tid][c];
            if (v < bv || (v == bv && idx < bi)) { bv = v; bi = idx; }
        }
        out[rbase + tid] = bi;
    }
}

// ---------------------------------------------------------------- launch
extern "C" void kernel_launch(void* const* d_in, const int* in_sizes, int n_in,
                              void* d_out, int out_size, void* d_ws, size_t ws_size,
                              hipStream_t stream) {
    const float* X  = (const float*)d_in[0];   // (8192, 320)
    // d_in[1]: mask_time_indices — statically all-ones, N stays 8192 -> unused
    const float* W  = (const float*)d_in[2];   // (512, 320)
    const float* CB = (const float*)d_in[3];   // (8192, 512)
    int* out = (int*)d_out;                    // (8192,) int32 indices

    float* targets = (float*)d_ws;                                  // 16.78 MB
    float* c2      = (float*)((char*)d_ws + (size_t)N_ROWS * CODE_DIM * 4);

    // c2[j] = ||code_j||^2 : 8192 waves = 2048 blocks of 4 waves
    c2_kernel<<<NUM_CODES / 4, 256, 0, stream>>>(CB, c2);

    // targets = X @ W^T
    dim3 pgrid(N_ROWS / PB_M, CODE_DIM / PB_N);
    proj_kernel<<<pgrid, 256, 0, stream>>>(X, W, targets);

    // fused distance + argmin
    dist_argmin_kernel<<<N_ROWS / DB_ROWS, 256, 0, stream>>>(targets, CB, c2, out);
}

// Round 7
// 1067.651 us; speedup vs baseline: 2.9297x; 2.9297x over previous
//
#include <hip/hip_runtime.h>

// RandomProjectionQuantizer: out[n] = argmin_j || x_n @ W^T - c_j ||^2
//   == argmin_j ( c2[j] - 2 * t_n . c_j )   (row-constant ||t||^2 dropped)
//
// R2: two-phase distance pass. Phase A: 64x64 grid of blocks, each computes a
// 128-row x 128-code tile with 8x8 register microtiles and reduces to per-row
// (best,idx) partials. Phase B: wave-per-row lexicographic reduce of the 64
// partials. Fixes R1's 1-block/CU occupancy wall (grid was 256 blocks).

#define D_IN      320
#define CODE_DIM  512
#define NUM_CODES 8192
#define N_ROWS    8192

// ---------------------------------------------------------------- c2 kernel
__global__ __launch_bounds__(256) void c2_kernel(const float* __restrict__ cb,
                                                 float* __restrict__ c2) {
    int wave = (blockIdx.x * blockDim.x + threadIdx.x) >> 6;
    int lane = threadIdx.x & 63;
    if (wave >= NUM_CODES) return;
    const float* row = cb + (size_t)wave * CODE_DIM;
    float s = 0.f;
#pragma unroll
    for (int i = 0; i < CODE_DIM / 64; ++i) {
        float v = row[lane + 64 * i];
        s += v * v;
    }
#pragma unroll
    for (int off = 32; off > 0; off >>= 1) s += __shfl_down(s, off, 64);
    if (lane == 0) c2[wave] = s;
}

// ------------------------------------------------------------ projection
// T = X @ W^T : M=8192, N=512, K=320. 64x64 tile, 256 thr, 4x4 microtile.
#define PB_M 64
#define PB_N 64
#define PB_K 32
#define PLD  (PB_K + 4)

__global__ __launch_bounds__(256) void proj_kernel(const float* __restrict__ X,
                                                   const float* __restrict__ W,
                                                   float* __restrict__ T) {
    __shared__ float Xs[PB_M][PLD];
    __shared__ float Wsh[PB_N][PLD];
    const int bm = blockIdx.x;
    const int bn = blockIdx.y;
    const int tid = threadIdx.x;
    const int tx = tid & 15;
    const int ty = tid >> 4;
    float acc[4][4] = {};
    for (int kc = 0; kc < D_IN; kc += PB_K) {
#pragma unroll
        for (int it = 0; it < 2; ++it) {
            int idx = tid + 256 * it;
            int r   = idx >> 3;
            int kp  = (idx & 7) * 4;
            *(float4*)&Xs[r][kp] =
                *(const float4*)(X + (size_t)(bm * PB_M + r) * D_IN + kc + kp);
            *(float4*)&Wsh[r][kp] =
                *(const float4*)(W + (size_t)(bn * PB_N + r) * D_IN + kc + kp);
        }
        __syncthreads();
#pragma unroll
        for (int kk = 0; kk < PB_K; ++kk) {
            float a[4], b[4];
#pragma unroll
            for (int i = 0; i < 4; ++i) a[i] = Xs[ty + 16 * i][kk];
#pragma unroll
            for (int j = 0; j < 4; ++j) b[j] = Wsh[tx + 16 * j][kk];
#pragma unroll
            for (int i = 0; i < 4; ++i)
#pragma unroll
                for (int j = 0; j < 4; ++j) acc[i][j] += a[i] * b[j];
        }
        __syncthreads();
    }
#pragma unroll
    for (int i = 0; i < 4; ++i)
#pragma unroll
        for (int j = 0; j < 4; ++j)
            T[(size_t)(bm * PB_M + ty + 16 * i) * CODE_DIM + bn * PB_N + tx + 16 * j] =
                acc[i][j];
}

// ------------------------------------- phase A: 128x128 tile dist + argmin
#define TM  128
#define TN  128
#define TK  32
#define LDT (TK + 4)   // 36 floats: 16B-aligned rows, banks 4*r mod 32

__global__ __launch_bounds__(256) void dist_tile_kernel(
        const float* __restrict__ T, const float* __restrict__ CB,
        const float* __restrict__ c2, float2* __restrict__ part) {
    __shared__ float t_lds[TM][LDT];   // 18.4 KB
    __shared__ float c_lds[TN][LDT];   // 18.4 KB

    const int tid = threadIdx.x;
    const int tx  = tid & 15;          // code groups: codes tx + 16j
    const int ty  = tid >> 4;          // row  groups: rows  ty + 16i
    const int rb  = blockIdx.y * TM;
    const int cb  = blockIdx.x * TN;

    float acc[8][8] = {};
    for (int kc = 0; kc < CODE_DIM; kc += TK) {
#pragma unroll
        for (int it = 0; it < 4; ++it) {
            int idx = tid + 256 * it;          // 0..1023: 128 rows x 8 float4
            int r   = idx >> 3;
            int kp  = (idx & 7) * 4;
            *(float4*)&t_lds[r][kp] =
                *(const float4*)(T + (size_t)(rb + r) * CODE_DIM + kc + kp);
            *(float4*)&c_lds[r][kp] =
                *(const float4*)(CB + (size_t)(cb + r) * CODE_DIM + kc + kp);
        }
        __syncthreads();
#pragma unroll 1
        for (int kk = 0; kk < TK; kk += 4) {
            float4 a[8], b[8];
#pragma unroll
            for (int i = 0; i < 8; ++i)
                a[i] = *(const float4*)&t_lds[ty + 16 * i][kk];
#pragma unroll
            for (int j = 0; j < 8; ++j)
                b[j] = *(const float4*)&c_lds[tx + 16 * j][kk];
#pragma unroll
            for (int i = 0; i < 8; ++i)
#pragma unroll
                for (int j = 0; j < 8; ++j)
                    acc[i][j] += a[i].x * b[j].x + a[i].y * b[j].y +
                                 a[i].z * b[j].z + a[i].w * b[j].w;
        }
        __syncthreads();
    }

    // per-thread argmin per row over its 8 codes (j ascending => code ascending)
    float bestv[8];
    int   besti[8];
#pragma unroll
    for (int i = 0; i < 8; ++i) { bestv[i] = 3.4e38f; besti[i] = 0x7fffffff; }
#pragma unroll
    for (int j = 0; j < 8; ++j) {
        int   code = cb + tx + 16 * j;
        float cc   = c2[code];
#pragma unroll
        for (int i = 0; i < 8; ++i) {
            float s = cc - 2.0f * acc[i][j];
            if (s < bestv[i]) { bestv[i] = s; besti[i] = code; }
        }
    }

    // cross-tx reduce: overlay reduction buffers on the (now dead) tiles
    float* rv = &t_lds[0][0];          // 128*16 floats
    int*   ri = (int*)&c_lds[0][0];    // 128*16 ints
#pragma unroll
    for (int i = 0; i < 8; ++i) {
        rv[(ty + 16 * i) * 16 + tx] = bestv[i];
        ri[(ty + 16 * i) * 16 + tx] = besti[i];
    }
    __syncthreads();
    if (tid < TM) {
        float bv = rv[tid * 16];
        int   bi = ri[tid * 16];
#pragma unroll
        for (int t = 1; t < 16; ++t) {
            float v  = rv[tid * 16 + t];
            int   ix = ri[tid * 16 + t];
            if (v < bv || (v == bv && ix < bi)) { bv = v; bi = ix; }
        }
        part[(size_t)(rb + tid) * (NUM_CODES / TN) + blockIdx.x] =
            make_float2(bv, __int_as_float(bi));
    }
}

// ---------------------------- phase B: reduce 64 partials/row, wave per row
__global__ __launch_bounds__(256) void argmin_reduce_kernel(
        const float2* __restrict__ part, int* __restrict__ out) {
    int row  = blockIdx.x * 4 + (threadIdx.x >> 6);
    int lane = threadIdx.x & 63;
    float2 p = part[(size_t)row * 64 + lane];
    float bv = p.x;
    int   bi = __float_as_int(p.y);
#pragma unroll
    for (int off = 32; off > 0; off >>= 1) {
        float ov = __shfl_down(bv, off, 64);
        int   oi = __shfl_down(bi, off, 64);
        if (ov < bv || (ov == bv && oi < bi)) { bv = ov; bi = oi; }
    }
    if (lane == 0) out[row] = bi;
}

// ---------------------------------------------------------------- launch
extern "C" void kernel_launch(void* const* d_in, const int* in_sizes, int n_in,
                              void* d_out, int out_size, void* d_ws, size_t ws_size,
                              hipStream_t stream) {
    const float* X  = (const float*)d_in[0];   // (8192, 320)
    // d_in[1]: mask_time_indices — statically all-ones -> unused
    const float* W  = (const float*)d_in[2];   // (512, 320)
    const float* CB = (const float*)d_in[3];   // (8192, 512)
    int* out = (int*)d_out;                    // (8192,) int32 indices

    char* ws = (char*)d_ws;
    float*  targets = (float*)ws;                                   // 16.78 MB
    float*  c2      = (float*)(ws + (size_t)N_ROWS * CODE_DIM * 4); // 32 KB
    float2* part    = (float2*)(ws + (size_t)N_ROWS * CODE_DIM * 4 + NUM_CODES * 4);
                                                                    // 4.19 MB

    c2_kernel<<<NUM_CODES / 4, 256, 0, stream>>>(CB, c2);

    dim3 pgrid(N_ROWS / PB_M, CODE_DIM / PB_N);
    proj_kernel<<<pgrid, 256, 0, stream>>>(X, W, targets);

    dim3 dgrid(NUM_CODES / TN, N_ROWS / TM);   // (64, 64) = 4096 blocks
    dist_tile_kernel<<<dgrid, 256, 0, stream>>>(targets, CB, c2, part);

    argmin_reduce_kernel<<<N_ROWS / 4, 256, 0, stream>>>(part, out);
}

// Round 9
// 351.317 us; speedup vs baseline: 8.9034x; 3.0390x over previous
//
#include <hip/hip_runtime.h>

// RandomProjectionQuantizer: out[n] = argmin_j || x_n @ W^T - c_j ||^2
//   == argmin_j ( c2[j] - 2 * t_n . c_j )
//
// R8: distance GEMM moved to MFMA via fp16 hi/lo split (3-term):
//   dot = hi_t.hi_c + hi_t.lo_c + lo_t.hi_c  (error ~2^-22 rel, ~3e-5 abs on
//   scores vs top-2 gap ~9 -> argmin-exact w.h.p.). fp32 R2 path was LDS+VALU
//   balanced at ~1B/FMA: structural ~900us floor; MFMA pipe was idle.

#define D_IN      320
#define CODE_DIM  512
#define NUM_CODES 8192
#define N_ROWS    8192

typedef _Float16 f16;
typedef __attribute__((ext_vector_type(4))) _Float16 f16x4;
typedef __attribute__((ext_vector_type(8))) _Float16 f16x8;
typedef __attribute__((ext_vector_type(4))) float    f32x4;

// ---------------------------------------------------------------- c2 kernel
__global__ __launch_bounds__(256) void c2_kernel(const float* __restrict__ cb,
                                                 float* __restrict__ c2) {
    int wave = (blockIdx.x * blockDim.x + threadIdx.x) >> 6;
    int lane = threadIdx.x & 63;
    if (wave >= NUM_CODES) return;
    const float* row = cb + (size_t)wave * CODE_DIM;
    float s = 0.f;
#pragma unroll
    for (int i = 0; i < CODE_DIM / 64; ++i) {
        float v = row[lane + 64 * i];
        s += v * v;
    }
#pragma unroll
    for (int off = 32; off > 0; off >>= 1) s += __shfl_down(s, off, 64);
    if (lane == 0) c2[wave] = s;
}

// -------------------------------------------------- fp32 -> hi/lo fp16 split
__global__ __launch_bounds__(256) void cvt_kernel(const float* __restrict__ src,
                                                  f16* __restrict__ hi,
                                                  f16* __restrict__ lo, int n4) {
    int i = blockIdx.x * blockDim.x + threadIdx.x;
    if (i >= n4) return;
    float4 v = ((const float4*)src)[i];
    f16 h0 = (f16)v.x, h1 = (f16)v.y, h2 = (f16)v.z, h3 = (f16)v.w;
    f16x4 hv = {h0, h1, h2, h3};
    f16x4 lv = {(f16)(v.x - (float)h0), (f16)(v.y - (float)h1),
                (f16)(v.z - (float)h2), (f16)(v.w - (float)h3)};
    *(f16x4*)&hi[(size_t)i * 4] = hv;
    *(f16x4*)&lo[(size_t)i * 4] = lv;
}

// ------------------------------------------------------------ projection
// T = X @ W^T : M=8192, N=512, K=320. Epilogue writes hi/lo fp16 planes.
#define PB_M 64
#define PB_N 64
#define PB_K 32
#define PLD  (PB_K + 4)

__global__ __launch_bounds__(256) void proj_kernel(const float* __restrict__ X,
                                                   const float* __restrict__ W,
                                                   f16* __restrict__ Thi,
                                                   f16* __restrict__ Tlo) {
    __shared__ float Xs[PB_M][PLD];
    __shared__ float Wsh[PB_N][PLD];
    const int bm = blockIdx.x;
    const int bn = blockIdx.y;
    const int tid = threadIdx.x;
    const int tx = tid & 15;
    const int ty = tid >> 4;
    float acc[4][4] = {};
    for (int kc = 0; kc < D_IN; kc += PB_K) {
#pragma unroll
        for (int it = 0; it < 2; ++it) {
            int idx = tid + 256 * it;
            int r   = idx >> 3;
            int kp  = (idx & 7) * 4;
            *(float4*)&Xs[r][kp] =
                *(const float4*)(X + (size_t)(bm * PB_M + r) * D_IN + kc + kp);
            *(float4*)&Wsh[r][kp] =
                *(const float4*)(W + (size_t)(bn * PB_N + r) * D_IN + kc + kp);
        }
        __syncthreads();
#pragma unroll
        for (int kk = 0; kk < PB_K; ++kk) {
            float a[4], b[4];
#pragma unroll
            for (int i = 0; i < 4; ++i) a[i] = Xs[ty + 16 * i][kk];
#pragma unroll
            for (int j = 0; j < 4; ++j) b[j] = Wsh[tx + 16 * j][kk];
#pragma unroll
            for (int i = 0; i < 4; ++i)
#pragma unroll
                for (int j = 0; j < 4; ++j) acc[i][j] += a[i] * b[j];
        }
        __syncthreads();
    }
#pragma unroll
    for (int i = 0; i < 4; ++i)
#pragma unroll
        for (int j = 0; j < 4; ++j) {
            size_t idx = (size_t)(bm * PB_M + ty + 16 * i) * CODE_DIM +
                         bn * PB_N + tx + 16 * j;
            float v = acc[i][j];
            f16  h = (f16)v;
            Thi[idx] = h;
            Tlo[idx] = (f16)(v - (float)h);
        }
}

// -------------------------------- phase A: MFMA dist + fused argmin
// Block 128x128, 4 waves (2x2), wave tile 64x64 = 4x4 mfma_f32_16x16x32_f16.
// LDS rows are 64 f16 = 128B, XOR-swizzled: byte ^= (row&7)<<4 (T2 recipe).
#define BM 128
#define BN 128
#define BK 64

__global__ __launch_bounds__(256) void dist_mfma_kernel(
        const f16* __restrict__ Thi, const f16* __restrict__ Tlo,
        const f16* __restrict__ Chi, const f16* __restrict__ Clo,
        const float* __restrict__ c2, float2* __restrict__ part) {
    __shared__ f16 Ah[BM * BK], Al[BM * BK];    // 16 KB each
    __shared__ f16 Bh[BN * BK], Bl[BN * BK];
    __shared__ float red_v[BM][2];
    __shared__ int   red_i[BM][2];

    const int tid = threadIdx.x;
    const int l   = tid & 63;
    const int w   = tid >> 6;        // 0..3
    const int wr  = w >> 1;          // wave row 0..1
    const int wc  = w & 1;           // wave col 0..1
    const int rb  = blockIdx.y * BM;
    const int cbase = blockIdx.x * BN;

    f32x4 acc[4][4];
#pragma unroll
    for (int i = 0; i < 4; ++i)
#pragma unroll
        for (int j = 0; j < 4; ++j) acc[i][j] = (f32x4){0.f, 0.f, 0.f, 0.f};

    for (int kc = 0; kc < CODE_DIM; kc += BK) {
        __syncthreads();   // previous compute done before LDS overwrite
        // stage 4 planes: 128 rows x 64 f16 each; 4 x uint4 per thread per plane
#pragma unroll
        for (int it = 0; it < 4; ++it) {
            int idx = tid + 256 * it;         // 0..1023
            int r   = idx >> 3;               // 0..127
            int kp  = (idx & 7) * 8;          // f16 offset 0..56
            int db  = r * 128 + ((kp * 2) ^ ((r & 7) << 4));
            size_t ga = (size_t)(rb + r) * CODE_DIM + kc + kp;
            size_t gb = (size_t)(cbase + r) * CODE_DIM + kc + kp;
            *(uint4*)((char*)Ah + db) = *(const uint4*)(Thi + ga);
            *(uint4*)((char*)Al + db) = *(const uint4*)(Tlo + ga);
            *(uint4*)((char*)Bh + db) = *(const uint4*)(Chi + gb);
            *(uint4*)((char*)Bl + db) = *(const uint4*)(Clo + gb);
        }
        __syncthreads();
#pragma unroll
        for (int ks = 0; ks < 2; ++ks) {
            const int kb = ks * 64 + (l >> 4) * 16;   // byte offset in row
            f16x8 ah[4], al[4], bh[4], bl[4];
#pragma unroll
            for (int i = 0; i < 4; ++i) {
                int r   = wr * 64 + i * 16 + (l & 15);
                int off = r * 128 + (kb ^ ((r & 7) << 4));
                ah[i] = *(const f16x8*)((const char*)Ah + off);
                al[i] = *(const f16x8*)((const char*)Al + off);
            }
#pragma unroll
            for (int j = 0; j < 4; ++j) {
                int c   = wc * 64 + j * 16 + (l & 15);
                int off = c * 128 + (kb ^ ((c & 7) << 4));
                bh[j] = *(const f16x8*)((const char*)Bh + off);
                bl[j] = *(const f16x8*)((const char*)Bl + off);
            }
#pragma unroll
            for (int i = 0; i < 4; ++i)
#pragma unroll
                for (int j = 0; j < 4; ++j) {
                    acc[i][j] = __builtin_amdgcn_mfma_f32_16x16x32_f16(
                        ah[i], bh[j], acc[i][j], 0, 0, 0);
                    acc[i][j] = __builtin_amdgcn_mfma_f32_16x16x32_f16(
                        ah[i], bl[j], acc[i][j], 0, 0, 0);
                    acc[i][j] = __builtin_amdgcn_mfma_f32_16x16x32_f16(
                        al[i], bh[j], acc[i][j], 0, 0, 0);
                }
        }
    }

    // epilogue: C/D layout (verified m89/m91): row=(l>>4)*4+p, col=l&15.
    // per (i): per-lane argmin over j (codes ascending), butterfly over the
    // 16 lanes sharing rows; exact (val,idx) first-index tie-break.
#pragma unroll
    for (int i = 0; i < 4; ++i) {
        float bvv[4];
        int   bii[4];
#pragma unroll
        for (int p = 0; p < 4; ++p) { bvv[p] = 3.4e38f; bii[p] = 0x7fffffff; }
#pragma unroll
        for (int j = 0; j < 4; ++j) {
            int   code = cbase + wc * 64 + j * 16 + (l & 15);
            float cc   = c2[code];
#pragma unroll
            for (int p = 0; p < 4; ++p) {
                float s = cc - 2.0f * acc[i][j][p];
                if (s < bvv[p]) { bvv[p] = s; bii[p] = code; }
            }
        }
#pragma unroll
        for (int off = 1; off < 16; off <<= 1) {
#pragma unroll
            for (int p = 0; p < 4; ++p) {
                float ov = __shfl_xor(bvv[p], off, 64);
                int   oi = __shfl_xor(bii[p], off, 64);
                if (ov < bvv[p] || (ov == bvv[p] && oi < bii[p])) {
                    bvv[p] = ov; bii[p] = oi;
                }
            }
        }
        if ((l & 15) == 0) {
#pragma unroll
            for (int p = 0; p < 4; ++p) {
                int rloc = wr * 64 + i * 16 + (l >> 4) * 4 + p;
                red_v[rloc][wc] = bvv[p];
                red_i[rloc][wc] = bii[p];
            }
        }
    }
    __syncthreads();
    if (tid < BM) {
        float v0 = red_v[tid][0], v1 = red_v[tid][1];
        int   i0 = red_i[tid][0], i1 = red_i[tid][1];
        bool  t1 = (v1 < v0) || (v1 == v0 && i1 < i0);
        part[(size_t)(rb + tid) * (NUM_CODES / BN) + blockIdx.x] =
            make_float2(t1 ? v1 : v0, __int_as_float(t1 ? i1 : i0));
    }
}

// ---------------------------- phase B: reduce 64 partials/row, wave per row
__global__ __launch_bounds__(256) void argmin_reduce_kernel(
        const float2* __restrict__ part, int* __restrict__ out) {
    int row  = blockIdx.x * 4 + (threadIdx.x >> 6);
    int lane = threadIdx.x & 63;
    float2 p = part[(size_t)row * 64 + lane];
    float bv = p.x;
    int   bi = __float_as_int(p.y);
#pragma unroll
    for (int off = 32; off > 0; off >>= 1) {
        float ov = __shfl_down(bv, off, 64);
        int   oi = __shfl_down(bi, off, 64);
        if (ov < bv || (ov == bv && oi < bi)) { bv = ov; bi = oi; }
    }
    if (lane == 0) out[row] = bi;
}

// ---------------------------------------------------------------- launch
extern "C" void kernel_launch(void* const* d_in, const int* in_sizes, int n_in,
                              void* d_out, int out_size, void* d_ws, size_t ws_size,
                              hipStream_t stream) {
    const float* X  = (const float*)d_in[0];   // (8192, 320)
    // d_in[1]: mask_time_indices — statically all-ones -> unused
    const float* W  = (const float*)d_in[2];   // (512, 320)
    const float* CB = (const float*)d_in[3];   // (8192, 512)
    int* out = (int*)d_out;                    // (8192,) int32

    const size_t PLANE = (size_t)N_ROWS * CODE_DIM * sizeof(f16);  // 8 MB
    char* ws = (char*)d_ws;
    f16*    Thi = (f16*)(ws);
    f16*    Tlo = (f16*)(ws + PLANE);
    f16*    Chi = (f16*)(ws + 2 * PLANE);
    f16*    Clo = (f16*)(ws + 3 * PLANE);
    float*  c2  = (float*)(ws + 4 * PLANE);                        // 32 KB
    float2* part = (float2*)(ws + 4 * PLANE + NUM_CODES * sizeof(float)); // 4 MB

    c2_kernel<<<NUM_CODES / 4, 256, 0, stream>>>(CB, c2);

    cvt_kernel<<<(NUM_CODES * CODE_DIM / 4) / 256, 256, 0, stream>>>(
        CB, Chi, Clo, NUM_CODES * CODE_DIM / 4);

    dim3 pgrid(N_ROWS / PB_M, CODE_DIM / PB_N);
    proj_kernel<<<pgrid, 256, 0, stream>>>(X, W, Thi, Tlo);

    dim3 dgrid(NUM_CODES / BN, N_ROWS / BM);   // (64, 64)
    dist_mfma_kernel<<<dgrid, 256, 0, stream>>>(Thi, Tlo, Chi, Clo, c2, part);

    argmin_reduce_kernel<<<N_ROWS / 4, 256, 0, stream>>>(part, out);
}